// Round 2
// 595.985 us; speedup vs baseline: 1.4034x; 1.4034x over previous
//
#include <hip/hip_runtime.h>

#define N 2048
#define D 128
#define BB 16

typedef __attribute__((ext_vector_type(8))) short s16x8;   // 8 bf16 = 4 VGPR
typedef __attribute__((ext_vector_type(4))) float f32x4;   // MFMA acc

// Split two fp32 into packed bf16 hi (h) and bf16 lo (l) words.
// hi = truncate-to-bf16(x); lo = truncate-to-bf16(x - hi).  ~2^-16 rel total.
__device__ __forceinline__ void split2(float x0, float x1, unsigned& h, unsigned& l) {
    unsigned b0 = __float_as_uint(x0), b1 = __float_as_uint(x1);
    float r0 = x0 - __uint_as_float(b0 & 0xffff0000u);
    float r1 = x1 - __uint_as_float(b1 & 0xffff0000u);
    h = (b0 >> 16) | (b1 & 0xffff0000u);
    l = (__float_as_uint(r0) >> 16) | (__float_as_uint(r1) & 0xffff0000u);
}

// ---------------------------------------------------------------------------
// Kernel 0: zero the `out` region (rowsum accumulators live at out[b][i][0]).
// ---------------------------------------------------------------------------
__global__ __launch_bounds__(256) void zero_kernel(float4* __restrict__ p, int n4) {
    int i = blockIdx.x * 256 + threadIdx.x;
    const int stride = gridDim.x * 256;
    for (; i < n4; i += stride) p[i] = make_float4(0.f, 0.f, 0.f, 0.f);
}

// ---------------------------------------------------------------------------
// Kernel 1: E = exp(Q @ K^T) via bf16 hi/lo MFMA (3-term), 128x128 tile,
// 4 waves. Also atomically accumulates row sums of E into out[b][i][0].
// LDS: per-K-step (BK=32) hi/lo tiles of Q and K, 16B-granule XOR swizzle.
// ---------------------------------------------------------------------------
__global__ __launch_bounds__(256) void qk_kernel(const float* __restrict__ q,
                                                 const float* __restrict__ k,
                                                 float* __restrict__ attn,
                                                 float* __restrict__ outp) {
    __shared__ unsigned short Qh[128 * 32], Ql[128 * 32];
    __shared__ unsigned short Kh[128 * 32], Kl[128 * 32];
    const int t  = threadIdx.x;
    const int b  = blockIdx.z;
    const int ib = blockIdx.y * 128;
    const int jb = blockIdx.x * 128;
    const float* qp = q + ((size_t)b * N + ib) * D;
    const float* kp = k + ((size_t)b * N + jb) * D;

    const int lane = t & 63;
    const int w    = t >> 6;
    const int wr   = (w >> 1) * 64;   // wave row quadrant
    const int wc   = (w & 1) * 64;    // wave col quadrant
    const int l15  = lane & 15;
    const int l4   = lane >> 4;

    f32x4 acc[4][4] = {};

    for (int ks = 0; ks < 4; ++ks) {
        __syncthreads();
        // Stage Q/K [128 rows][32 k] fp32 -> hi/lo bf16 LDS (swizzled).
        #pragma unroll
        for (int c = 0; c < 4; ++c) {
            int flat = c * 256 + t;        // 1024 float4 per matrix
            int row  = flat >> 3;          // 8 float4 per row
            int f4   = flat & 7;
            float4 qv = *(const float4*)(qp + (size_t)row * D + ks * 32 + f4 * 4);
            float4 kv = *(const float4*)(kp + (size_t)row * D + ks * 32 + f4 * 4);
            int idx = row * 32 + (((f4 >> 1) ^ (row & 3)) * 8) + (f4 & 1) * 4;
            uint2 hh, ll;
            split2(qv.x, qv.y, hh.x, ll.x);
            split2(qv.z, qv.w, hh.y, ll.y);
            *(uint2*)(Qh + idx) = hh;
            *(uint2*)(Ql + idx) = ll;
            split2(kv.x, kv.y, hh.x, ll.x);
            split2(kv.z, kv.w, hh.y, ll.y);
            *(uint2*)(Kh + idx) = hh;
            *(uint2*)(Kl + idx) = ll;
        }
        __syncthreads();

        // Fragments: A lane reads Q[row=l15][8*l4 .. +7], B reads K-row likewise.
        s16x8 ah[4], al[4], bh[4], bl[4];
        #pragma unroll
        for (int ti = 0; ti < 4; ++ti) {
            int row = wr + ti * 16 + l15;
            int idx = row * 32 + ((l4 ^ (row & 3)) * 8);
            ah[ti] = *(const s16x8*)(Qh + idx);
            al[ti] = *(const s16x8*)(Ql + idx);
        }
        #pragma unroll
        for (int tj = 0; tj < 4; ++tj) {
            int row = wc + tj * 16 + l15;
            int idx = row * 32 + ((l4 ^ (row & 3)) * 8);
            bh[tj] = *(const s16x8*)(Kh + idx);
            bl[tj] = *(const s16x8*)(Kl + idx);
        }
        #pragma unroll
        for (int ti = 0; ti < 4; ++ti)
            #pragma unroll
            for (int tj = 0; tj < 4; ++tj) {
                acc[ti][tj] = __builtin_amdgcn_mfma_f32_16x16x32_bf16(ah[ti], bh[tj], acc[ti][tj], 0, 0, 0);
                acc[ti][tj] = __builtin_amdgcn_mfma_f32_16x16x32_bf16(ah[ti], bl[tj], acc[ti][tj], 0, 0, 0);
                acc[ti][tj] = __builtin_amdgcn_mfma_f32_16x16x32_bf16(al[ti], bh[tj], acc[ti][tj], 0, 0, 0);
            }
    }

    // Epilogue: E = exp(s) (no max subtraction needed: |s| <= ~70 < 88),
    // store E, reduce row partial sums over this block's 128 cols, atomicAdd.
    #pragma unroll
    for (int ti = 0; ti < 4; ++ti) {
        #pragma unroll
        for (int r = 0; r < 4; ++r) {
            int row = ib + wr + ti * 16 + l4 * 4 + r;
            float* arow = attn + ((size_t)b * N + row) * N + jb + wc;
            float rs = 0.f;
            #pragma unroll
            for (int tj = 0; tj < 4; ++tj) {
                float e = __expf(acc[ti][tj][r]);
                arow[tj * 16 + l15] = e;
                rs += e;
            }
            rs += __shfl_xor(rs, 1);
            rs += __shfl_xor(rs, 2);
            rs += __shfl_xor(rs, 4);
            rs += __shfl_xor(rs, 8);
            if (l15 == 0) atomicAdd(outp + ((size_t)b * N + row) * D, rs);
        }
    }
}

// ---------------------------------------------------------------------------
// Kernel 2: P = E * (1/rowsum) written back in-place to attn; O = P @ V via
// bf16 hi/lo MFMA. 64(i) x 128(d) tile, 4 waves, j-chunks of 64 with
// register prefetch of the next chunk. V transposed+split into LDS [d][j].
// ---------------------------------------------------------------------------
__global__ __launch_bounds__(256) void pv_kernel(const float* __restrict__ v,
                                                 float* __restrict__ attn,
                                                 float* __restrict__ outp) {
    __shared__ unsigned short Ph[64 * 64], Pl[64 * 64];
    __shared__ unsigned short Vth[128 * 64], Vtl[128 * 64];
    __shared__ float invs[64];
    const int t  = threadIdx.x;
    const int b  = blockIdx.y;
    const int ib = blockIdx.x * 64;
    float* ap       = attn + ((size_t)b * N + ib) * N;
    const float* vp = v + (size_t)b * N * D;
    float* op       = outp + ((size_t)b * N + ib) * D;

    if (t < 64) invs[t] = 1.0f / op[(size_t)t * D];   // rowsum from QK atomics

    const int lane = t & 63;
    const int w    = t >> 6;
    const int rg   = (w >> 1) * 32;   // wave row group (32 rows)
    const int dg   = (w & 1) * 64;    // wave d group (64 cols)
    const int l15  = lane & 15;
    const int l4   = lane >> 4;

    f32x4 acc[2][4] = {};

    // Register prefetch buffers for one j-chunk: E (4x float4), V (4x2 float4).
    float4 pe[4], va[4], vb[4];
    #pragma unroll
    for (int c = 0; c < 4; ++c) {
        int flat = c * 256 + t;
        pe[c] = *(const float4*)(ap + (size_t)(flat >> 4) * N + (flat & 15) * 4);
        int jp = flat >> 5, d4 = flat & 31;
        va[c] = *(const float4*)(vp + (size_t)(jp * 2) * D + d4 * 4);
        vb[c] = *(const float4*)(vp + (size_t)(jp * 2 + 1) * D + d4 * 4);
    }

    for (int jc = 0; jc < 32; ++jc) {
        __syncthreads();   // LDS free (prev compute done); also fences invs on jc=0
        // Stage P: p = E*inv; write normalized attn in-place; hi/lo -> LDS.
        #pragma unroll
        for (int c = 0; c < 4; ++c) {
            int flat = c * 256 + t;
            int row = flat >> 4, j4 = flat & 15;
            float iv = invs[row];
            float4 p4;
            p4.x = pe[c].x * iv; p4.y = pe[c].y * iv;
            p4.z = pe[c].z * iv; p4.w = pe[c].w * iv;
            *(float4*)(ap + (size_t)row * N + jc * 64 + j4 * 4) = p4;
            uint2 hh, ll;
            split2(p4.x, p4.y, hh.x, ll.x);
            split2(p4.z, p4.w, hh.y, ll.y);
            int idx = row * 64 + (((j4 >> 1) ^ (row & 7)) * 8) + (j4 & 1) * 4;
            *(uint2*)(Ph + idx) = hh;
            *(uint2*)(Pl + idx) = ll;
        }
        // Stage V transposed: Vt[d][j] hi/lo bf16 (pair of j's packed per b32).
        #pragma unroll
        for (int c = 0; c < 4; ++c) {
            int flat = c * 256 + t;
            int jp = flat >> 5, d4 = flat & 31;
            int j = jp * 2;
            float4 v0 = va[c], v1 = vb[c];
            #pragma unroll
            for (int e = 0; e < 4; ++e) {
                float x0 = (&v0.x)[e], x1 = (&v1.x)[e];
                unsigned h, l;
                split2(x0, x1, h, l);
                int d = d4 * 4 + e;
                int idx = d * 64 + (((j >> 3) ^ (d & 7)) * 8) + (j & 7);
                *(unsigned*)(Vth + idx) = h;
                *(unsigned*)(Vtl + idx) = l;
            }
        }
        __syncthreads();
        // Prefetch next chunk (hides HBM latency under MFMA below).
        if (jc < 31) {
            #pragma unroll
            for (int c = 0; c < 4; ++c) {
                int flat = c * 256 + t;
                pe[c] = *(const float4*)(ap + (size_t)(flat >> 4) * N + (jc + 1) * 64 + (flat & 15) * 4);
                int jp = flat >> 5, d4 = flat & 31;
                va[c] = *(const float4*)(vp + (size_t)((jc + 1) * 64 + jp * 2) * D + d4 * 4);
                vb[c] = *(const float4*)(vp + (size_t)((jc + 1) * 64 + jp * 2 + 1) * D + d4 * 4);
            }
        }
        // Compute: 2 K-steps of 32 over this chunk's 64 j.
        #pragma unroll
        for (int ksj = 0; ksj < 2; ++ksj) {
            s16x8 pah[2], pal[2], bh[4], bl[4];
            #pragma unroll
            for (int ti = 0; ti < 2; ++ti) {
                int row = rg + ti * 16 + l15;
                int idx = row * 64 + (((ksj * 4 + l4) ^ (row & 7)) * 8);
                pah[ti] = *(const s16x8*)(Ph + idx);
                pal[ti] = *(const s16x8*)(Pl + idx);
            }
            #pragma unroll
            for (int tj = 0; tj < 4; ++tj) {
                int d = dg + tj * 16 + l15;
                int idx = d * 64 + (((ksj * 4 + l4) ^ (d & 7)) * 8);
                bh[tj] = *(const s16x8*)(Vth + idx);
                bl[tj] = *(const s16x8*)(Vtl + idx);
            }
            #pragma unroll
            for (int ti = 0; ti < 2; ++ti)
                #pragma unroll
                for (int tj = 0; tj < 4; ++tj) {
                    acc[ti][tj] = __builtin_amdgcn_mfma_f32_16x16x32_bf16(pah[ti], bh[tj], acc[ti][tj], 0, 0, 0);
                    acc[ti][tj] = __builtin_amdgcn_mfma_f32_16x16x32_bf16(pah[ti], bl[tj], acc[ti][tj], 0, 0, 0);
                    acc[ti][tj] = __builtin_amdgcn_mfma_f32_16x16x32_bf16(pal[ti], bh[tj], acc[ti][tj], 0, 0, 0);
                }
        }
    }

    // Epilogue: write O (also overwrites the rowsum scratch at d=0).
    #pragma unroll
    for (int ti = 0; ti < 2; ++ti)
        #pragma unroll
        for (int r = 0; r < 4; ++r) {
            int row = rg + ti * 16 + l4 * 4 + r;
            #pragma unroll
            for (int tj = 0; tj < 4; ++tj)
                op[(size_t)row * D + dg + tj * 16 + l15] = acc[ti][tj][r];
        }
}

extern "C" void kernel_launch(void* const* d_in, const int* in_sizes, int n_in,
                              void* d_out, int out_size, void* d_ws, size_t ws_size,
                              hipStream_t stream) {
    const float* q = (const float*)d_in[0];
    const float* k = (const float*)d_in[1];
    const float* v = (const float*)d_in[2];
    float* out  = (float*)d_out;                    // [16,2048,128]
    float* attn = out + (size_t)BB * N * D;         // [16,2048,2048]

    zero_kernel<<<1024, 256, 0, stream>>>((float4*)out, BB * N * D / 4);
    qk_kernel<<<dim3(N / 128, N / 128, BB), 256, 0, stream>>>(q, k, attn, out);
    pv_kernel<<<dim3(N / 64, BB), 256, 0, stream>>>(v, attn, out);
}